// Round 2
// baseline (123.119 us; speedup 1.0000x reference)
//
#include <hip/hip_runtime.h>

#define SRC_LEN 256
#define TRG_LEN 256
#define BATCH   32
#define HID     512
#define ATT     128
#define CSCALE  2.885390081777927f   // 2*log2(e): exp2(CSCALE*x) == exp(2x)

typedef float  f32x4  __attribute__((ext_vector_type(4)));
typedef short  bf16x8 __attribute__((ext_vector_type(8)));

// manual RNE fp32->bf16 (inputs are finite normals; NaN path not needed)
__device__ inline unsigned short bfr(float x) {
    unsigned u = __builtin_bit_cast(unsigned, x);
    return (unsigned short)((u + 0x7fffu + ((u >> 16) & 1u)) >> 16);
}
__device__ inline unsigned pk2(float a, float b) {
    return (unsigned)bfr(a) | ((unsigned)bfr(b) << 16);
}

// ---------------------------------------------------------------------------
// Prep: (1) convert W_s/W_t to bf16 MFMA-B-fragment layout so proj can load
// each B-fragment as ONE coalesced global_load_dwordx4 (L2-resident, shared
// by all blocks) instead of staging W through LDS every chunk; (2) sumv.
// Fragment algebra replicates the validated LDS swizzle read: for a-tile,
// chunk c, half s, lane l holds W[a_tile*16+(l&15)][c*64+s*32+(l>>4)*8+j].
// Layout: Wb[iw][a_tile(8)][c(8)][s(2)][lane(64)] as uint4 (16 B/frag-lane).
// ---------------------------------------------------------------------------
__global__ __launch_bounds__(256) void prep_kernel(
    const float* __restrict__ W_s, const float* __restrict__ W_t,
    const float* __restrict__ v_a,
    uint4* __restrict__ Wb, float* __restrict__ sumvP)
{
    const int blk = blockIdx.x;
    if (blk < 16) {
        const int iw = blk >> 3, a_tile = blk & 7;
        const float* __restrict__ W = iw ? W_t : W_s;
        uint4* __restrict__ dst = Wb + ((size_t)iw * 8 + a_tile) * 1024;
        #pragma unroll
        for (int oo = 0; oo < 4; ++oo) {
            const int o = threadIdx.x + oo * 256;        // 0..1023 = (c*2+s)*64+lane
            const int c = o >> 7, rem = o & 127;
            const int s = rem >> 6, lane = rem & 63;
            const int q = lane >> 4, l15 = lane & 15;
            const int row = a_tile * 16 + l15;
            const int k0 = c * 64 + s * 32 + q * 8;
            const float4 f0 = *(const float4*)(W + (size_t)row * HID + k0);
            const float4 f1 = *(const float4*)(W + (size_t)row * HID + k0 + 4);
            uint4 u;
            u.x = pk2(f0.x, f0.y); u.y = pk2(f0.z, f0.w);
            u.z = pk2(f1.x, f1.y); u.w = pk2(f1.z, f1.w);
            dst[o] = u;
        }
    } else {
        const int tid = threadIdx.x;
        float x = 0.f;
        if (tid < 64) x = v_a[tid] + v_a[tid + 64];
        #pragma unroll
        for (int o = 32; o > 0; o >>= 1) x += __shfl_down(x, o);
        if (tid == 0) *sumvP = x;
    }
}

// ---------------------------------------------------------------------------
// MFMA projection v8: W staging removed (prebuilt bf16 fragments, direct
// coalesced global loads, L2-served). A-only LDS staging: 16-row tiles,
// 256 threads (4 waves, each wave owns 32 a-cols = 2 frags), 1024 blocks
// -> 4 independent blocks/CU, so per-chunk vmcnt drains of one block hide
// under the MFMA/loads of the other three (independent barriers). Per chunk
// per thread: 1x16B global A load + 2 pk2 + 1 ds_write_b64 -- ~1/5 of the
// old staging work. Same validated swizzle/fragment algebra throughout.
// ---------------------------------------------------------------------------
__global__ __launch_bounds__(256, 4) void proj_mfma(
    const float* __restrict__ dec_out, const float* __restrict__ enc_outs,
    const float* __restrict__ b_t, const uint4* __restrict__ Wb,
    float* __restrict__ encE, float* __restrict__ decD)
{
    __shared__ __align__(16) char smem[8704];   // A dbuf 2*2 KB; T overlay 8448 B

    const int tid   = threadIdx.x;
    const int blk   = blockIdx.x;
    const bool isDec = blk >= 512;
    const int blkL  = isDec ? blk - 512 : blk;
    const int bb    = blkL & 31;
    const int r0    = (blkL >> 5) * 16;          // s0 or t0 (16-row tile)
    const float* __restrict__ in = isDec ? dec_out : enc_outs;
    const uint4* __restrict__ Wk = Wb + (isDec ? 8192 : 0);

    const int lane = tid & 63;
    const int w    = tid >> 6;                   // 0..3
    const int woff_n = w * 32;
    const int q = lane >> 4, l15 = lane & 15, l7 = lane & 7;

    // A staging: row srow = tid>>4 (0..15), float4 col skc = tid&15.
    const int srow = tid >> 4;
    const int skc  = tid & 15;
    const int sg   = skc >> 1, shalf = skc & 1;
    const float* aGp = in + ((size_t)(r0 + srow) * BATCH + bb) * HID + skc * 4;

    float4 aR;
    f32x4 acc[2];
    acc[0] = (f32x4)0.0f;
    acc[1] = (f32x4)0.0f;

    #define LOADG(c) { aR = *(const float4*)(aGp + (size_t)(c) * 64); }
    #define STORES(buf)                                                      \
        {                                                                    \
            char* ab = smem + (buf) * 2048;                                  \
            uint2 u;                                                         \
            u.x = pk2(aR.x, aR.y);                                           \
            u.y = pk2(aR.z, aR.w);                                           \
            *(uint2*)(ab + srow * 128 + ((sg ^ (srow & 7)) << 4)             \
                      + shalf * 8) = u;                                      \
        }

    LOADG(0);
    STORES(0);
    __syncthreads();

    for (int c = 0; c < 8; ++c) {
        if (c < 7) LOADG(c + 1);
        const char* ab = smem + (c & 1) * 2048;
        #pragma unroll
        for (int s = 0; s < 2; ++s) {
            bf16x8 af = *(const bf16x8*)(ab + l15 * 128
                                         + (((s * 4 + q) ^ l7) << 4));
            #pragma unroll
            for (int ni = 0; ni < 2; ++ni) {
                const int a_tile = w * 2 + ni;
                bf16x8 bfv = *(const bf16x8*)(Wk + (((a_tile * 8 + c) * 2 + s) * 64 + lane));
                acc[ni] = __builtin_amdgcn_mfma_f32_16x16x32_bf16(
                    af, bfv, acc[ni], 0, 0, 0);
            }
        }
        if (c < 7) STORES((c + 1) & 1);
        __syncthreads();
    }

    if (!isDec) {
        // E' = exp(-2*enc_att) -> LDS transpose (stride 132) -> [b][a>>2][s][4]
        float* T = (float*)smem;
        #pragma unroll
        for (int ni = 0; ni < 2; ++ni)
            #pragma unroll
            for (int r = 0; r < 4; ++r) {
                const int ml = q * 4 + r;               // 0..15 (s-local)
                const int nl = woff_n + ni * 16 + l15;  // 0..127 (a)
                T[ml * 132 + nl] = __builtin_amdgcn_exp2f(-CSCALE * acc[ni][r]);
            }
        __syncthreads();
        {
            const int m  = tid & 15;     // s-local
            const int g0 = tid >> 4;     // 0..15
            #pragma unroll
            for (int p = 0; p < 2; ++p) {
                const int gq = g0 + p * 16;             // a-quad 0..31
                float4 v = *(const float4*)(T + m * 132 + gq * 4);
                *(float4*)(encE + (((size_t)bb * 32 + gq) * SRC_LEN + r0 + m) * 4) = v;
            }
        }
    } else {
        // D = exp(+2*(dec_att + b_t)), natural [t][b][a] store
        float bt[2];
        bt[0] = b_t[woff_n + l15];
        bt[1] = b_t[woff_n + 16 + l15];
        #pragma unroll
        for (int ni = 0; ni < 2; ++ni)
            #pragma unroll
            for (int r = 0; r < 4; ++r) {
                const int ml = q * 4 + r;
                const int nl = woff_n + ni * 16 + l15;
                decD[((size_t)(r0 + ml) * BATCH + bb) * ATT + nl] =
                    __builtin_amdgcn_exp2f(CSCALE * (acc[ni][r] + bt[ni]));
            }
    }
    #undef LOADG
    #undef STORES
}

// ---------------------------------------------------------------------------
// Score v8: ZERO LDS. v6/v7 were LDS-pipe-bound: 5 ds_read_b128 per g ->
// 5120 b128/CU x ~12 cyc = ~25.6 us of LDS pipe (vs ~13 us VALU). All d and
// v operands are WAVE-UNIFORM (indices depend only on blockIdx) -> read them
// directly from global with uniform addresses: compiler emits s_load_dwordx4
// (scalar cache, 2 KB working set/block, hot) and every VALU op takes its
// single legal SGPR operand. sumv comes precomputed from prep (SALU has no
// float add; avoids LDS reduce). Floor moves to the ~13 us VALU roofline.
// ---------------------------------------------------------------------------
__global__ __launch_bounds__(256) void score_kernel(
    const float* __restrict__ encE, const float* __restrict__ decD,
    const float* __restrict__ v_a, const float* __restrict__ sumvP,
    float* __restrict__ out)
{
    const int tid = threadIdx.x;
    const int t0  = blockIdx.x * 4;
    const int b   = blockIdx.y;

    float acc0 = 0.f, acc1 = 0.f, acc2 = 0.f, acc3 = 0.f;
    const float* __restrict__ ep = encE + ((size_t)b * 32 * SRC_LEN + tid) * 4;
    const float* __restrict__ dBase = decD + ((size_t)t0 * BATCH + b) * ATT;  // uniform

    #pragma unroll
    for (int g = 0; g < 32; ++g) {
        const float4 E  = *(const float4*)(ep + (size_t)g * SRC_LEN * 4);
        const float4 vv = *(const float4*)(v_a + g * 4);            // s_load
        const float n0 = vv.x * E.x, n1 = vv.y * E.y;
        const float n2 = vv.z * E.z, n3 = vv.w * E.w;

        #define TSTEP(ACC, TT)                                             \
        {                                                                  \
            const float4 d = *(const float4*)(dBase                        \
                + (size_t)(TT) * BATCH * ATT + g * 4);   /* s_load */      \
            const float x0 = E.x + d.x, x1 = E.y + d.y;                    \
            const float x2 = E.z + d.z, x3 = E.w + d.w;                    \
            const float a01 = x0 * x1, a23 = x2 * x3;                      \
            const float den = a01 * a23;                                   \
            const float m01 = fmaf(n0, x1, n1 * x0);                       \
            const float m23 = fmaf(n2, x3, n3 * x2);                       \
            const float num = fmaf(m01, a23, m23 * a01);                   \
            ACC = fmaf(num, __builtin_amdgcn_rcpf(den), ACC);              \
        }
        TSTEP(acc0, 0)
        TSTEP(acc1, 1)
        TSTEP(acc2, 2)
        TSTEP(acc3, 3)
        #undef TSTEP
    }

    const float sv = *sumvP;                                        // s_load
    out[((size_t)(t0 + 0) * BATCH + b) * SRC_LEN + tid] = sv - 2.0f * acc0;
    out[((size_t)(t0 + 1) * BATCH + b) * SRC_LEN + tid] = sv - 2.0f * acc1;
    out[((size_t)(t0 + 2) * BATCH + b) * SRC_LEN + tid] = sv - 2.0f * acc2;
    out[((size_t)(t0 + 3) * BATCH + b) * SRC_LEN + tid] = sv - 2.0f * acc3;
}

extern "C" void kernel_launch(void* const* d_in, const int* in_sizes, int n_in,
                              void* d_out, int out_size, void* d_ws, size_t ws_size,
                              hipStream_t stream) {
    const float* dec_out  = (const float*)d_in[0];
    const float* enc_outs = (const float*)d_in[1];
    const float* W_s      = (const float*)d_in[2];
    const float* W_t      = (const float*)d_in[3];
    const float* b_t      = (const float*)d_in[4];
    const float* v_a      = (const float*)d_in[5];
    float* out = (float*)d_out;

    float* encE = (float*)d_ws;                              // B*32*S*4 = 4 MB : exp(-2*enc_att), [b][a>>2][s][4]
    float* decD = encE + (size_t)BATCH * ATT * SRC_LEN;      // T*B*A    = 4 MB : exp(+2*dec_att), [t][b][a]
    uint4* Wb   = (uint4*)(decD + (size_t)TRG_LEN * BATCH * ATT);  // 256 KB bf16 W fragments
    float* sumvP = (float*)(Wb + 2 * 8192);                  // 4 B

    prep_kernel<<<17, 256, 0, stream>>>(W_s, W_t, v_a, Wb, sumvP);
    proj_mfma<<<1024, 256, 0, stream>>>(dec_out, enc_outs, b_t, Wb, encE, decD);
    score_kernel<<<dim3(TRG_LEN / 4, BATCH), 256, 0, stream>>>(encE, decD, v_a, sumvP, out);
}